// Round 1
// baseline (226.532 us; speedup 1.0000x reference)
//
#include <hip/hip_runtime.h>
#include <math.h>

#define NUM_CITIES 88
#define NUM_YEARS 6
#define N_ROWS 200000

#define COL4 (NUM_CITIES / 4)            // 22 float4 groups per row
#define TOT4 (N_ROWS * COL4)             // 4,400,000 float4 elems in G/D/w
#define DIFF2 (N_ROWS * NUM_YEARS / 2)   // 600,000 float2 elems in U/out

#define NBLK 1936                        // NBLK*256 % 22 == 0
#define NTHREADS (NBLK * 256)            // 495616
#define NPART 92                         // 88 colsums + 4 scalars per block

// 8 guaranteed iterations per thread; tail (9th) for gtid < TAIL_CUT.
#define TAIL_CUT (TOT4 - 8 * NTHREADS)

// ws layout: [NPART][NBLK] partials (transposed for coalesced reduce reads),
// then 92 stage-2 sums, then 1 atomic counter word.
#define WS2_OFF (NPART * NBLK)
#define CTR_OFF (WS2_OFF + NPART)

typedef float vf4 __attribute__((ext_vector_type(4)));
typedef float vf2 __attribute__((ext_vector_type(2)));

// PLAIN cached loads. The working set (G+D+w+U+out ~= 221 MB) fits in the
// 256 MiB Infinity Cache; nontemporal (evict-first) hints were forcing ~50%
// of reads back to HBM on every replay (FETCH_SIZE 107.8 MB of 221 MB read).
static __device__ __forceinline__ vf4 ld4(const float* p) {
    return *(const vf4*)p;
}
static __device__ __forceinline__ vf2 ld2(const float* p) {
    return *(const vf2*)p;
}

__global__ __launch_bounds__(256) void loss_main(
    const float* __restrict__ G,
    const float* __restrict__ outm,
    const float* __restrict__ U,
    const float* __restrict__ D,
    const float* __restrict__ w,
    float* __restrict__ ws)
{
    __shared__ float scol[NUM_CITIES];
    __shared__ float ssum[4];

    const int tid = threadIdx.x;
    const int gtid = blockIdx.x * blockDim.x + tid;
    const int c0 = (gtid % COL4) * 4;    // fixed column group (NTHREADS % 22 == 0)

    // ---- issue all 24 loads for the 8 guaranteed iterations ----
    vf4 g0 = ld4(G + 4 * ((size_t)gtid + 0 * NTHREADS));
    vf4 g1 = ld4(G + 4 * ((size_t)gtid + 1 * NTHREADS));
    vf4 g2 = ld4(G + 4 * ((size_t)gtid + 2 * NTHREADS));
    vf4 g3 = ld4(G + 4 * ((size_t)gtid + 3 * NTHREADS));
    vf4 g4 = ld4(G + 4 * ((size_t)gtid + 4 * NTHREADS));
    vf4 g5 = ld4(G + 4 * ((size_t)gtid + 5 * NTHREADS));
    vf4 g6 = ld4(G + 4 * ((size_t)gtid + 6 * NTHREADS));
    vf4 g7 = ld4(G + 4 * ((size_t)gtid + 7 * NTHREADS));
    vf4 d0 = ld4(D + 4 * ((size_t)gtid + 0 * NTHREADS));
    vf4 d1 = ld4(D + 4 * ((size_t)gtid + 1 * NTHREADS));
    vf4 d2 = ld4(D + 4 * ((size_t)gtid + 2 * NTHREADS));
    vf4 d3 = ld4(D + 4 * ((size_t)gtid + 3 * NTHREADS));
    vf4 d4 = ld4(D + 4 * ((size_t)gtid + 4 * NTHREADS));
    vf4 d5 = ld4(D + 4 * ((size_t)gtid + 5 * NTHREADS));
    vf4 d6 = ld4(D + 4 * ((size_t)gtid + 6 * NTHREADS));
    vf4 d7 = ld4(D + 4 * ((size_t)gtid + 7 * NTHREADS));
    vf4 v0 = ld4(w + 4 * ((size_t)gtid + 0 * NTHREADS));
    vf4 v1 = ld4(w + 4 * ((size_t)gtid + 1 * NTHREADS));
    vf4 v2 = ld4(w + 4 * ((size_t)gtid + 2 * NTHREADS));
    vf4 v3 = ld4(w + 4 * ((size_t)gtid + 3 * NTHREADS));
    vf4 v4 = ld4(w + 4 * ((size_t)gtid + 4 * NTHREADS));
    vf4 v5 = ld4(w + 4 * ((size_t)gtid + 5 * NTHREADS));
    vf4 v6 = ld4(w + 4 * ((size_t)gtid + 6 * NTHREADS));
    vf4 v7 = ld4(w + 4 * ((size_t)gtid + 7 * NTHREADS));

    float ca0 = 0.f, ca1 = 0.f, ca2 = 0.f, ca3 = 0.f;
    float s_r2 = 0.f, s_w2 = 0.f, s_neg = 0.f;

#define ACC(g, d, v)                                                          \
    {                                                                         \
        ca0 += fabsf(g.x); ca1 += fabsf(g.y);                                 \
        ca2 += fabsf(g.z); ca3 += fabsf(g.w);                                 \
        float r0 = g.x - v.x * d.x, r1 = g.y - v.y * d.y;                     \
        float r2 = g.z - v.z * d.z, r3 = g.w - v.w * d.w;                     \
        s_r2 += r0 * r0 + r1 * r1 + r2 * r2 + r3 * r3;                        \
        s_w2 += v.x * v.x + v.y * v.y + v.z * v.z + v.w * v.w;                \
        s_neg += fminf(g.x, 0.f) + fminf(g.y, 0.f)                            \
               + fminf(g.z, 0.f) + fminf(g.w, 0.f);                          \
    }

    ACC(g0, d0, v0) ACC(g1, d1, v1) ACC(g2, d2, v2) ACC(g3, d3, v3)
    ACC(g4, d4, v4) ACC(g5, d5, v5) ACC(g6, d6, v6) ACC(g7, d7, v7)

    // tail iteration (stride preserves gtid % 22 -> same column group)
    if (gtid < TAIL_CUT) {
        vf4 g = ld4(G + 4 * ((size_t)gtid + 8 * NTHREADS));
        vf4 d = ld4(D + 4 * ((size_t)gtid + 8 * NTHREADS));
        vf4 v = ld4(w + 4 * ((size_t)gtid + 8 * NTHREADS));
        ACC(g, d, v)
    }
#undef ACC

    // ---- (U - out)^2 over first 5 of every 6 columns, float2-vectorized ----
    float s_diff = 0.f;
    {
        vf2 u = ld2(U + 2 * (size_t)gtid), o = ld2(outm + 2 * (size_t)gtid);
        float dx = u.x - o.x, dy = u.y - o.y;
        s_diff += dx * dx + ((gtid % 3 != 2) ? dy * dy : 0.f);
        const int i2 = gtid + NTHREADS;
        if (i2 < DIFF2) {
            vf2 u2 = ld2(U + 2 * (size_t)i2), o2 = ld2(outm + 2 * (size_t)i2);
            float ex = u2.x - o2.x, ey = u2.y - o2.y;
            s_diff += ex * ex + ((i2 % 3 != 2) ? ey * ey : 0.f);
        }
    }

    // ---- block-level reduction (LDS only) ----
    if (tid < NUM_CITIES) scol[tid] = 0.f;
    if (tid < 4) ssum[tid] = 0.f;
    __syncthreads();

    atomicAdd(&scol[c0 + 0], ca0);
    atomicAdd(&scol[c0 + 1], ca1);
    atomicAdd(&scol[c0 + 2], ca2);
    atomicAdd(&scol[c0 + 3], ca3);

    for (int off = 32; off > 0; off >>= 1) {
        s_diff += __shfl_down(s_diff, off);
        s_r2   += __shfl_down(s_r2, off);
        s_w2   += __shfl_down(s_w2, off);
        s_neg  += __shfl_down(s_neg, off);
    }
    if ((tid & 63) == 0) {
        atomicAdd(&ssum[0], s_diff);
        atomicAdd(&ssum[1], s_r2);
        atomicAdd(&ssum[2], s_w2);
        atomicAdd(&ssum[3], s_neg);
    }
    __syncthreads();

    // transposed partials: ws[k][block] -> reduce kernel reads are coalesced
    if (tid < NUM_CITIES)
        ws[(size_t)tid * NBLK + blockIdx.x] = scol[tid];
    else if (tid < NPART)
        ws[(size_t)tid * NBLK + blockIdx.x] = ssum[tid - NUM_CITIES];
}

// Stage A+B merged: block k sums partial k over all NBLK blocks -> ws2[k];
// the last block to finish (atomic-counter handoff) computes the final loss.
// Counter condition uses (old % NPART) == NPART-1, so it needs no init and is
// correct for ANY starting value and any number of graph replays.
__global__ __launch_bounds__(256) void loss_reduce_fin(
    float* __restrict__ ws, float* __restrict__ out)
{
    const int k = blockIdx.x;
    const int t = threadIdx.x;

    const float* src = ws + (size_t)k * NBLK;
    float acc = 0.f;
    for (int b = t; b < NBLK; b += 256)
        acc += src[b];
    for (int off = 32; off > 0; off >>= 1) acc += __shfl_down(acc, off);

    __shared__ float s[4];
    __shared__ int last;
    if ((t & 63) == 0) s[t >> 6] = acc;
    __syncthreads();
    if (t == 0) {
        ws[WS2_OFF + k] = s[0] + s[1] + s[2] + s[3];
        __threadfence();  // make ws2[k] visible before signaling
        unsigned old = atomicAdd((unsigned int*)(ws + CTR_OFF), 1u);
        last = ((old % NPART) == (NPART - 1)) ? 1 : 0;
    }
    __syncthreads();
    if (!last) return;

    __threadfence();  // acquire: see all other blocks' ws2 writes
    const float* ws2 = ws + WS2_OFF;
    float v = 0.f;
    if (t < NUM_CITIES)      v = 1e-4f * logf(ws2[t]);
    else if (t == 88)        v = ws2[88];           // diff
    else if (t == 89)        v = 100.f * ws2[89];   // r2 * sg^2/se^2
    else if (t == 90)        v = 0.01f * ws2[90];   // w2 * se^2/sw^2
    else if (t == 91)        v = 100.f * ws2[91];   // neg penalty

    for (int off = 32; off > 0; off >>= 1) v += __shfl_down(v, off);
    __shared__ float sh[4];
    if ((t & 63) == 0) sh[t >> 6] = v;
    __syncthreads();
    if (t == 0) out[0] = sh[0] + sh[1] + sh[2] + sh[3];
}

extern "C" void kernel_launch(void* const* d_in, const int* in_sizes, int n_in,
                              void* d_out, int out_size, void* d_ws, size_t ws_size,
                              hipStream_t stream) {
    const float* G    = (const float*)d_in[0];
    const float* outm = (const float*)d_in[1];
    const float* U    = (const float*)d_in[2];
    // d_in[3] = V, unused by the reference
    const float* D    = (const float*)d_in[4];
    const float* w    = (const float*)d_in[5];
    float* out = (float*)d_out;
    float* ws  = (float*)d_ws;

    loss_main<<<NBLK, 256, 0, stream>>>(G, outm, U, D, w, ws);
    loss_reduce_fin<<<NPART, 256, 0, stream>>>(ws, out);
}

// Round 2
// 210.568 us; speedup vs baseline: 1.0758x; 1.0758x over previous
//
#include <hip/hip_runtime.h>
#include <math.h>

#define NUM_CITIES 88
#define NUM_YEARS 6
#define N_ROWS 200000

#define COL4 (NUM_CITIES / 4)            // 22 float4 groups per row
#define TOT4 (N_ROWS * COL4)             // 4,400,000 float4 elems in G/D/w
#define DIFF2 (N_ROWS * NUM_YEARS / 2)   // 600,000 float2 elems in U/out

#define NBLK 1936                        // NBLK*256 % 22 == 0
#define NTHREADS (NBLK * 256)            // 495616
#define NPART 92                         // 88 colsums + 4 scalars per block

// 8 guaranteed iterations per thread; tail (9th) for gtid < TAIL_CUT.
#define TAIL_CUT (TOT4 - 8 * NTHREADS)

// ws layout: [NPART][NBLK] partials (transposed for coalesced reduce reads),
// then 92 stage-2 sums, then 1 atomic counter word.
#define WS2_OFF (NPART * NBLK)
#define CTR_OFF (WS2_OFF + NPART)

typedef float vf4 __attribute__((ext_vector_type(4)));
typedef float vf2 __attribute__((ext_vector_type(2)));

// NONTEMPORAL loads are essential here (round-1 A/B: plain cached loads were
// 2x slower at identical FETCH_SIZE). The 221 MB stream has zero intra-dispatch
// reuse; plain loads allocate it into L1/L2, throttling the fill path and
// evicting the ws partial-write lines mid-combine (WRITE_SIZE 726KB -> 5.7MB).
// nt loads bypass allocation: clean L2, full-rate streaming.
static __device__ __forceinline__ vf4 ldnt4(const float* p) {
    return __builtin_nontemporal_load((const vf4*)p);
}
static __device__ __forceinline__ vf2 ldnt2(const float* p) {
    return __builtin_nontemporal_load((const vf2*)p);
}

__global__ __launch_bounds__(256) void loss_main(
    const float* __restrict__ G,
    const float* __restrict__ outm,
    const float* __restrict__ U,
    const float* __restrict__ D,
    const float* __restrict__ w,
    float* __restrict__ ws)
{
    __shared__ float scol[NUM_CITIES];
    __shared__ float ssum[4];

    const int tid = threadIdx.x;
    const int gtid = blockIdx.x * blockDim.x + tid;
    const int c0 = (gtid % COL4) * 4;    // fixed column group (NTHREADS % 22 == 0)

    // ---- issue all 24 nontemporal loads for the 8 guaranteed iterations ----
    vf4 g0 = ldnt4(G + 4 * ((size_t)gtid + 0 * NTHREADS));
    vf4 g1 = ldnt4(G + 4 * ((size_t)gtid + 1 * NTHREADS));
    vf4 g2 = ldnt4(G + 4 * ((size_t)gtid + 2 * NTHREADS));
    vf4 g3 = ldnt4(G + 4 * ((size_t)gtid + 3 * NTHREADS));
    vf4 g4 = ldnt4(G + 4 * ((size_t)gtid + 4 * NTHREADS));
    vf4 g5 = ldnt4(G + 4 * ((size_t)gtid + 5 * NTHREADS));
    vf4 g6 = ldnt4(G + 4 * ((size_t)gtid + 6 * NTHREADS));
    vf4 g7 = ldnt4(G + 4 * ((size_t)gtid + 7 * NTHREADS));
    vf4 d0 = ldnt4(D + 4 * ((size_t)gtid + 0 * NTHREADS));
    vf4 d1 = ldnt4(D + 4 * ((size_t)gtid + 1 * NTHREADS));
    vf4 d2 = ldnt4(D + 4 * ((size_t)gtid + 2 * NTHREADS));
    vf4 d3 = ldnt4(D + 4 * ((size_t)gtid + 3 * NTHREADS));
    vf4 d4 = ldnt4(D + 4 * ((size_t)gtid + 4 * NTHREADS));
    vf4 d5 = ldnt4(D + 4 * ((size_t)gtid + 5 * NTHREADS));
    vf4 d6 = ldnt4(D + 4 * ((size_t)gtid + 6 * NTHREADS));
    vf4 d7 = ldnt4(D + 4 * ((size_t)gtid + 7 * NTHREADS));
    vf4 v0 = ldnt4(w + 4 * ((size_t)gtid + 0 * NTHREADS));
    vf4 v1 = ldnt4(w + 4 * ((size_t)gtid + 1 * NTHREADS));
    vf4 v2 = ldnt4(w + 4 * ((size_t)gtid + 2 * NTHREADS));
    vf4 v3 = ldnt4(w + 4 * ((size_t)gtid + 3 * NTHREADS));
    vf4 v4 = ldnt4(w + 4 * ((size_t)gtid + 4 * NTHREADS));
    vf4 v5 = ldnt4(w + 4 * ((size_t)gtid + 5 * NTHREADS));
    vf4 v6 = ldnt4(w + 4 * ((size_t)gtid + 6 * NTHREADS));
    vf4 v7 = ldnt4(w + 4 * ((size_t)gtid + 7 * NTHREADS));

    float ca0 = 0.f, ca1 = 0.f, ca2 = 0.f, ca3 = 0.f;
    float s_r2 = 0.f, s_w2 = 0.f, s_neg = 0.f;

#define ACC(g, d, v)                                                          \
    {                                                                         \
        ca0 += fabsf(g.x); ca1 += fabsf(g.y);                                 \
        ca2 += fabsf(g.z); ca3 += fabsf(g.w);                                 \
        float r0 = g.x - v.x * d.x, r1 = g.y - v.y * d.y;                     \
        float r2 = g.z - v.z * d.z, r3 = g.w - v.w * d.w;                     \
        s_r2 += r0 * r0 + r1 * r1 + r2 * r2 + r3 * r3;                        \
        s_w2 += v.x * v.x + v.y * v.y + v.z * v.z + v.w * v.w;                \
        s_neg += fminf(g.x, 0.f) + fminf(g.y, 0.f)                            \
               + fminf(g.z, 0.f) + fminf(g.w, 0.f);                          \
    }

    ACC(g0, d0, v0) ACC(g1, d1, v1) ACC(g2, d2, v2) ACC(g3, d3, v3)
    ACC(g4, d4, v4) ACC(g5, d5, v5) ACC(g6, d6, v6) ACC(g7, d7, v7)

    // tail iteration (stride preserves gtid % 22 -> same column group)
    if (gtid < TAIL_CUT) {
        vf4 g = ldnt4(G + 4 * ((size_t)gtid + 8 * NTHREADS));
        vf4 d = ldnt4(D + 4 * ((size_t)gtid + 8 * NTHREADS));
        vf4 v = ldnt4(w + 4 * ((size_t)gtid + 8 * NTHREADS));
        ACC(g, d, v)
    }
#undef ACC

    // ---- (U - out)^2 over first 5 of every 6 columns, float2-vectorized ----
    float s_diff = 0.f;
    {
        vf2 u = ldnt2(U + 2 * (size_t)gtid), o = ldnt2(outm + 2 * (size_t)gtid);
        float dx = u.x - o.x, dy = u.y - o.y;
        s_diff += dx * dx + ((gtid % 3 != 2) ? dy * dy : 0.f);
        const int i2 = gtid + NTHREADS;
        if (i2 < DIFF2) {
            vf2 u2 = ldnt2(U + 2 * (size_t)i2), o2 = ldnt2(outm + 2 * (size_t)i2);
            float ex = u2.x - o2.x, ey = u2.y - o2.y;
            s_diff += ex * ex + ((i2 % 3 != 2) ? ey * ey : 0.f);
        }
    }

    // ---- block-level reduction (LDS only) ----
    if (tid < NUM_CITIES) scol[tid] = 0.f;
    if (tid < 4) ssum[tid] = 0.f;
    __syncthreads();

    atomicAdd(&scol[c0 + 0], ca0);
    atomicAdd(&scol[c0 + 1], ca1);
    atomicAdd(&scol[c0 + 2], ca2);
    atomicAdd(&scol[c0 + 3], ca3);

    for (int off = 32; off > 0; off >>= 1) {
        s_diff += __shfl_down(s_diff, off);
        s_r2   += __shfl_down(s_r2, off);
        s_w2   += __shfl_down(s_w2, off);
        s_neg  += __shfl_down(s_neg, off);
    }
    if ((tid & 63) == 0) {
        atomicAdd(&ssum[0], s_diff);
        atomicAdd(&ssum[1], s_r2);
        atomicAdd(&ssum[2], s_w2);
        atomicAdd(&ssum[3], s_neg);
    }
    __syncthreads();

    // transposed partials: ws[k][block] -> reduce kernel reads are coalesced
    if (tid < NUM_CITIES)
        ws[(size_t)tid * NBLK + blockIdx.x] = scol[tid];
    else if (tid < NPART)
        ws[(size_t)tid * NBLK + blockIdx.x] = ssum[tid - NUM_CITIES];
}

// Stage A+B merged: block k sums partial k over all NBLK blocks -> ws2[k];
// the last block to finish (atomic-counter handoff) computes the final loss.
// Counter condition uses (old % NPART) == NPART-1, so it needs no init and is
// correct for ANY starting value and any number of graph replays.
__global__ __launch_bounds__(256) void loss_reduce_fin(
    float* __restrict__ ws, float* __restrict__ out)
{
    const int k = blockIdx.x;
    const int t = threadIdx.x;

    const float* src = ws + (size_t)k * NBLK;
    float acc = 0.f;
    for (int b = t; b < NBLK; b += 256)
        acc += src[b];
    for (int off = 32; off > 0; off >>= 1) acc += __shfl_down(acc, off);

    __shared__ float s[4];
    __shared__ int last;
    if ((t & 63) == 0) s[t >> 6] = acc;
    __syncthreads();
    if (t == 0) {
        ws[WS2_OFF + k] = s[0] + s[1] + s[2] + s[3];
        __threadfence();  // make ws2[k] visible before signaling
        unsigned old = atomicAdd((unsigned int*)(ws + CTR_OFF), 1u);
        last = ((old % NPART) == (NPART - 1)) ? 1 : 0;
    }
    __syncthreads();
    if (!last) return;

    __threadfence();  // acquire: see all other blocks' ws2 writes
    const float* ws2 = ws + WS2_OFF;
    float v = 0.f;
    if (t < NUM_CITIES)      v = 1e-4f * logf(ws2[t]);
    else if (t == 88)        v = ws2[88];           // diff
    else if (t == 89)        v = 100.f * ws2[89];   // r2 * sg^2/se^2
    else if (t == 90)        v = 0.01f * ws2[90];   // w2 * se^2/sw^2
    else if (t == 91)        v = 100.f * ws2[91];   // neg penalty

    for (int off = 32; off > 0; off >>= 1) v += __shfl_down(v, off);
    __shared__ float sh[4];
    if ((t & 63) == 0) sh[t >> 6] = v;
    __syncthreads();
    if (t == 0) out[0] = sh[0] + sh[1] + sh[2] + sh[3];
}

extern "C" void kernel_launch(void* const* d_in, const int* in_sizes, int n_in,
                              void* d_out, int out_size, void* d_ws, size_t ws_size,
                              hipStream_t stream) {
    const float* G    = (const float*)d_in[0];
    const float* outm = (const float*)d_in[1];
    const float* U    = (const float*)d_in[2];
    // d_in[3] = V, unused by the reference
    const float* D    = (const float*)d_in[4];
    const float* w    = (const float*)d_in[5];
    float* out = (float*)d_out;
    float* ws  = (float*)d_ws;

    loss_main<<<NBLK, 256, 0, stream>>>(G, outm, U, D, w, ws);
    loss_reduce_fin<<<NPART, 256, 0, stream>>>(ws, out);
}

// Round 4
// 206.628 us; speedup vs baseline: 1.0963x; 1.0191x over previous
//
#include <hip/hip_runtime.h>
#include <math.h>

#define NUM_CITIES 88
#define NUM_YEARS 6
#define N_ROWS 200000

#define COL4 (NUM_CITIES / 4)            // 22 float4 groups per row
#define TOT4 (N_ROWS * COL4)             // 4,400,000 float4 elems in G/D/w
#define DIFF2 (N_ROWS * NUM_YEARS / 2)   // 600,000 float2 elems in U/out

// NBLK = 11*256: satisfies NTHREADS % 22 == 0 (column-group trick) AND is an
// exact multiple of 256 CUs -> 11 blocks/CU, no dispatch-tail imbalance
// (previous NBLK=1936 gave 144 CUs x8 blocks + 112 CUs x7 -> ~6% idle tail).
#define NBLK 2816
#define NTHREADS (NBLK * 256)            // 720896 = 22 * 32768

#define NPART 92                         // 88 colsums + 4 scalars per block

// 6 guaranteed iterations per thread; tail (7th) for gtid < TAIL_CUT.
#define TAIL_CUT (TOT4 - 6 * NTHREADS)   // 74624

// ws layout: [NBLK][NPART] contiguous partials (6-7 lines per block store,
// round-0 measured 726 KB WRITE_SIZE vs 5.6 MB transposed), then 92 stage-2
// sums, then 1 atomic counter word for the last-block handoff (2nd kernel).
#define WS2_OFF (NBLK * NPART)
#define CTR_OFF (WS2_OFF + NPART)

typedef float vf4 __attribute__((ext_vector_type(4)));
typedef float vf2 __attribute__((ext_vector_type(2)));

// NONTEMPORAL loads are essential (round-1/2 A/B: plain cached loads = 2x
// slower at identical FETCH_SIZE; the 221 MB stream has zero reuse and L2
// allocation throttles the fill path). nt bypasses allocation.
static __device__ __forceinline__ vf4 ldnt4(const float* p) {
    return __builtin_nontemporal_load((const vf4*)p);
}
static __device__ __forceinline__ vf2 ldnt2(const float* p) {
    return __builtin_nontemporal_load((const vf2*)p);
}

__global__ __launch_bounds__(256) void loss_main(
    const float* __restrict__ G,
    const float* __restrict__ outm,
    const float* __restrict__ U,
    const float* __restrict__ D,
    const float* __restrict__ w,
    float* __restrict__ ws)
{
    __shared__ float scol[NUM_CITIES];
    __shared__ float ssum[4];

    const int tid = threadIdx.x;
    const int gtid = blockIdx.x * blockDim.x + tid;
    const int c0 = (gtid % COL4) * 4;    // fixed column group (NTHREADS % 22 == 0)

    // ---- issue all 18 nontemporal loads for the 6 guaranteed iterations ----
    vf4 g0 = ldnt4(G + 4 * ((size_t)gtid + 0 * NTHREADS));
    vf4 g1 = ldnt4(G + 4 * ((size_t)gtid + 1 * NTHREADS));
    vf4 g2 = ldnt4(G + 4 * ((size_t)gtid + 2 * NTHREADS));
    vf4 g3 = ldnt4(G + 4 * ((size_t)gtid + 3 * NTHREADS));
    vf4 g4 = ldnt4(G + 4 * ((size_t)gtid + 4 * NTHREADS));
    vf4 g5 = ldnt4(G + 4 * ((size_t)gtid + 5 * NTHREADS));
    vf4 d0 = ldnt4(D + 4 * ((size_t)gtid + 0 * NTHREADS));
    vf4 d1 = ldnt4(D + 4 * ((size_t)gtid + 1 * NTHREADS));
    vf4 d2 = ldnt4(D + 4 * ((size_t)gtid + 2 * NTHREADS));
    vf4 d3 = ldnt4(D + 4 * ((size_t)gtid + 3 * NTHREADS));
    vf4 d4 = ldnt4(D + 4 * ((size_t)gtid + 4 * NTHREADS));
    vf4 d5 = ldnt4(D + 4 * ((size_t)gtid + 5 * NTHREADS));
    vf4 v0 = ldnt4(w + 4 * ((size_t)gtid + 0 * NTHREADS));
    vf4 v1 = ldnt4(w + 4 * ((size_t)gtid + 1 * NTHREADS));
    vf4 v2 = ldnt4(w + 4 * ((size_t)gtid + 2 * NTHREADS));
    vf4 v3 = ldnt4(w + 4 * ((size_t)gtid + 3 * NTHREADS));
    vf4 v4 = ldnt4(w + 4 * ((size_t)gtid + 4 * NTHREADS));
    vf4 v5 = ldnt4(w + 4 * ((size_t)gtid + 5 * NTHREADS));

    float ca0 = 0.f, ca1 = 0.f, ca2 = 0.f, ca3 = 0.f;
    float s_r2 = 0.f, s_w2 = 0.f, s_neg = 0.f;

#define ACC(g, d, v)                                                          \
    {                                                                         \
        ca0 += fabsf(g.x); ca1 += fabsf(g.y);                                 \
        ca2 += fabsf(g.z); ca3 += fabsf(g.w);                                 \
        float r0 = g.x - v.x * d.x, r1 = g.y - v.y * d.y;                     \
        float r2 = g.z - v.z * d.z, r3 = g.w - v.w * d.w;                     \
        s_r2 += r0 * r0 + r1 * r1 + r2 * r2 + r3 * r3;                        \
        s_w2 += v.x * v.x + v.y * v.y + v.z * v.z + v.w * v.w;                \
        s_neg += fminf(g.x, 0.f) + fminf(g.y, 0.f)                            \
               + fminf(g.z, 0.f) + fminf(g.w, 0.f);                          \
    }

    ACC(g0, d0, v0) ACC(g1, d1, v1) ACC(g2, d2, v2)
    ACC(g3, d3, v3) ACC(g4, d4, v4) ACC(g5, d5, v5)

    // tail iteration (stride preserves gtid % 22 -> same column group)
    if (gtid < TAIL_CUT) {
        vf4 g = ldnt4(G + 4 * ((size_t)gtid + 6 * NTHREADS));
        vf4 d = ldnt4(D + 4 * ((size_t)gtid + 6 * NTHREADS));
        vf4 v = ldnt4(w + 4 * ((size_t)gtid + 6 * NTHREADS));
        ACC(g, d, v)
    }
#undef ACC

    // ---- (U - out)^2 over first 5 of every 6 columns, float2-vectorized ----
    // NTHREADS > DIFF2, so each thread handles at most one float2 pair.
    float s_diff = 0.f;
    if (gtid < DIFF2) {
        vf2 u = ldnt2(U + 2 * (size_t)gtid), o = ldnt2(outm + 2 * (size_t)gtid);
        float dx = u.x - o.x, dy = u.y - o.y;
        s_diff = dx * dx + ((gtid % 3 != 2) ? dy * dy : 0.f);
    }

    // ---- block-level reduction (LDS only) ----
    if (tid < NUM_CITIES) scol[tid] = 0.f;
    if (tid < 4) ssum[tid] = 0.f;
    __syncthreads();

    atomicAdd(&scol[c0 + 0], ca0);
    atomicAdd(&scol[c0 + 1], ca1);
    atomicAdd(&scol[c0 + 2], ca2);
    atomicAdd(&scol[c0 + 3], ca3);

    for (int off = 32; off > 0; off >>= 1) {
        s_diff += __shfl_down(s_diff, off);
        s_r2   += __shfl_down(s_r2, off);
        s_w2   += __shfl_down(s_w2, off);
        s_neg  += __shfl_down(s_neg, off);
    }
    if ((tid & 63) == 0) {
        atomicAdd(&ssum[0], s_diff);
        atomicAdd(&ssum[1], s_r2);
        atomicAdd(&ssum[2], s_w2);
        atomicAdd(&ssum[3], s_neg);
    }
    __syncthreads();

    // contiguous per-block partial store
    float* dst = ws + (size_t)blockIdx.x * NPART;
    if (tid < NUM_CITIES)     dst[tid] = scol[tid];
    else if (tid < NPART)     dst[tid] = ssum[tid - NUM_CITIES];
}

// Stage A+B merged (round-2-validated pattern): block k sums partial k over
// all NBLK blocks -> ws2[k]; last block (atomic-counter handoff, replay-safe
// (old % NPART)==NPART-1 condition, no init needed) computes the final loss.
// Partials come from a PREVIOUS dispatch -> no intra-dispatch cross-XCD
// visibility hazard (round-3 lesson).
__global__ __launch_bounds__(256) void loss_reduce_fin(
    float* __restrict__ ws, float* __restrict__ out)
{
    const int k = blockIdx.x;
    const int t = threadIdx.x;

    // strided reads: ws[b*NPART + k], b = t, t+256, ... (11 iterations)
    float acc = 0.f;
    for (int b = t; b < NBLK; b += 256)
        acc += ws[(size_t)b * NPART + k];
    for (int off = 32; off > 0; off >>= 1) acc += __shfl_down(acc, off);

    __shared__ float s[4];
    __shared__ int last;
    if ((t & 63) == 0) s[t >> 6] = acc;
    __syncthreads();
    if (t == 0) {
        ws[WS2_OFF + k] = s[0] + s[1] + s[2] + s[3];
        __threadfence();  // make ws2[k] visible before signaling
        unsigned old = atomicAdd((unsigned int*)(ws + CTR_OFF), 1u);
        last = ((old % NPART) == (NPART - 1)) ? 1 : 0;
    }
    __syncthreads();
    if (!last) return;

    __threadfence();  // acquire: see all other blocks' ws2 writes
    const float* ws2 = ws + WS2_OFF;
    float v = 0.f;
    if (t < NUM_CITIES)      v = 1e-4f * logf(ws2[t]);
    else if (t == 88)        v = ws2[88];           // diff
    else if (t == 89)        v = 100.f * ws2[89];   // r2 * sg^2/se^2
    else if (t == 90)        v = 0.01f * ws2[90];   // w2 * se^2/sw^2
    else if (t == 91)        v = 100.f * ws2[91];   // neg penalty

    for (int off = 32; off > 0; off >>= 1) v += __shfl_down(v, off);
    __shared__ float sh[4];
    if ((t & 63) == 0) sh[t >> 6] = v;
    __syncthreads();
    if (t == 0) out[0] = sh[0] + sh[1] + sh[2] + sh[3];
}

extern "C" void kernel_launch(void* const* d_in, const int* in_sizes, int n_in,
                              void* d_out, int out_size, void* d_ws, size_t ws_size,
                              hipStream_t stream) {
    const float* G    = (const float*)d_in[0];
    const float* outm = (const float*)d_in[1];
    const float* U    = (const float*)d_in[2];
    // d_in[3] = V, unused by the reference
    const float* D    = (const float*)d_in[4];
    const float* w    = (const float*)d_in[5];
    float* out = (float*)d_out;
    float* ws  = (float*)d_ws;

    loss_main<<<NBLK, 256, 0, stream>>>(G, outm, U, D, w, ws);
    loss_reduce_fin<<<NPART, 256, 0, stream>>>(ws, out);
}

// Round 5
// 204.998 us; speedup vs baseline: 1.1050x; 1.0080x over previous
//
#include <hip/hip_runtime.h>
#include <math.h>

#define NUM_CITIES 88
#define NUM_YEARS 6
#define N_ROWS 200000

#define COL4 (NUM_CITIES / 4)            // 22 float4 groups per row
#define TOT4 (N_ROWS * COL4)             // 4,400,000 float4 elems in G/D/w
#define DIFF4 (N_ROWS * NUM_YEARS / 4)   // 300,000 float4 elems in U/out

// NBLK = 11*256: satisfies NTHREADS % 22 == 0 (column-group trick) AND is an
// exact multiple of 256 CUs -> 11 blocks/CU, no dispatch-tail imbalance.
#define NBLK 2816
#define NTHREADS (NBLK * 256)            // 720896 = 22 * 32768

#define NPART 92                         // 88 colsums + 4 scalars per block
#define NPART4 (NPART / 4)               // 23 vf4 groups

// 6 guaranteed iterations per thread; tail (7th) for gtid < TAIL_CUT.
#define TAIL_CUT (TOT4 - 6 * NTHREADS)   // 74624

// ws layout: [NBLK][NPART] contiguous partials (few lines per block store,
// measured WRITE_SIZE 1056 KB), then 92 stage-2 sums, then 1 atomic counter
// word for the last-block handoff inside the 2nd dispatch.
#define WS2_OFF (NBLK * NPART)
#define CTR_OFF (WS2_OFF + NPART)

typedef float vf4 __attribute__((ext_vector_type(4)));

// NONTEMPORAL loads are essential (round-1/2 A/B: plain cached loads = 2x
// slower at identical FETCH_SIZE; the 221 MB stream has zero reuse and L2
// allocation throttles the fill path). nt bypasses allocation.
static __device__ __forceinline__ vf4 ldnt4(const float* p) {
    return __builtin_nontemporal_load((const vf4*)p);
}

__global__ __launch_bounds__(256) void loss_main(
    const float* __restrict__ G,
    const float* __restrict__ outm,
    const float* __restrict__ U,
    const float* __restrict__ D,
    const float* __restrict__ w,
    float* __restrict__ ws)
{
    __shared__ float scol[NUM_CITIES];
    __shared__ float ssum[4];

    const int tid = threadIdx.x;
    const int gtid = blockIdx.x * blockDim.x + tid;
    const int c0 = (gtid % COL4) * 4;    // fixed column group (NTHREADS % 22 == 0)

    // ---- issue all 18 nontemporal loads for the 6 guaranteed iterations ----
    vf4 g0 = ldnt4(G + 4 * ((size_t)gtid + 0 * NTHREADS));
    vf4 g1 = ldnt4(G + 4 * ((size_t)gtid + 1 * NTHREADS));
    vf4 g2 = ldnt4(G + 4 * ((size_t)gtid + 2 * NTHREADS));
    vf4 g3 = ldnt4(G + 4 * ((size_t)gtid + 3 * NTHREADS));
    vf4 g4 = ldnt4(G + 4 * ((size_t)gtid + 4 * NTHREADS));
    vf4 g5 = ldnt4(G + 4 * ((size_t)gtid + 5 * NTHREADS));
    vf4 d0 = ldnt4(D + 4 * ((size_t)gtid + 0 * NTHREADS));
    vf4 d1 = ldnt4(D + 4 * ((size_t)gtid + 1 * NTHREADS));
    vf4 d2 = ldnt4(D + 4 * ((size_t)gtid + 2 * NTHREADS));
    vf4 d3 = ldnt4(D + 4 * ((size_t)gtid + 3 * NTHREADS));
    vf4 d4 = ldnt4(D + 4 * ((size_t)gtid + 4 * NTHREADS));
    vf4 d5 = ldnt4(D + 4 * ((size_t)gtid + 5 * NTHREADS));
    vf4 v0 = ldnt4(w + 4 * ((size_t)gtid + 0 * NTHREADS));
    vf4 v1 = ldnt4(w + 4 * ((size_t)gtid + 1 * NTHREADS));
    vf4 v2 = ldnt4(w + 4 * ((size_t)gtid + 2 * NTHREADS));
    vf4 v3 = ldnt4(w + 4 * ((size_t)gtid + 3 * NTHREADS));
    vf4 v4 = ldnt4(w + 4 * ((size_t)gtid + 4 * NTHREADS));
    vf4 v5 = ldnt4(w + 4 * ((size_t)gtid + 5 * NTHREADS));

    float ca0 = 0.f, ca1 = 0.f, ca2 = 0.f, ca3 = 0.f;
    float s_r2 = 0.f, s_w2 = 0.f, s_neg = 0.f;

#define ACC(g, d, v)                                                          \
    {                                                                         \
        ca0 += fabsf(g.x); ca1 += fabsf(g.y);                                 \
        ca2 += fabsf(g.z); ca3 += fabsf(g.w);                                 \
        float r0 = g.x - v.x * d.x, r1 = g.y - v.y * d.y;                     \
        float r2 = g.z - v.z * d.z, r3 = g.w - v.w * d.w;                     \
        s_r2 += r0 * r0 + r1 * r1 + r2 * r2 + r3 * r3;                        \
        s_w2 += v.x * v.x + v.y * v.y + v.z * v.z + v.w * v.w;                \
        s_neg += fminf(g.x, 0.f) + fminf(g.y, 0.f)                            \
               + fminf(g.z, 0.f) + fminf(g.w, 0.f);                          \
    }

    ACC(g0, d0, v0) ACC(g1, d1, v1) ACC(g2, d2, v2)
    ACC(g3, d3, v3) ACC(g4, d4, v4) ACC(g5, d5, v5)

    // tail iteration (stride preserves gtid % 22 -> same column group)
    if (gtid < TAIL_CUT) {
        vf4 g = ldnt4(G + 4 * ((size_t)gtid + 6 * NTHREADS));
        vf4 d = ldnt4(D + 4 * ((size_t)gtid + 6 * NTHREADS));
        vf4 v = ldnt4(w + 4 * ((size_t)gtid + 6 * NTHREADS));
        ACC(g, d, v)
    }
#undef ACC

    // ---- (U - out)^2 over first 5 of every 6 columns, float4-vectorized ----
    // float4 j covers year-columns (4j..4j+3) mod 6:
    //   j%3==0 -> cols 0,1,2,3 (keep all)
    //   j%3==1 -> cols 4,5,0,1 (drop elem 1)
    //   j%3==2 -> cols 2,3,4,5 (drop elem 3)
    float s_diff = 0.f;
    if (gtid < DIFF4) {
        vf4 u = ldnt4(U + 4 * (size_t)gtid), o = ldnt4(outm + 4 * (size_t)gtid);
        const int m = gtid % 3;
        float e0 = u.x - o.x, e1 = u.y - o.y, e2 = u.z - o.z, e3 = u.w - o.w;
        s_diff = e0 * e0 + e2 * e2
               + ((m != 1) ? e1 * e1 : 0.f)
               + ((m != 2) ? e3 * e3 : 0.f);
    }

    // ---- block-level reduction (LDS only) ----
    if (tid < NUM_CITIES) scol[tid] = 0.f;
    if (tid < 4) ssum[tid] = 0.f;
    __syncthreads();

    atomicAdd(&scol[c0 + 0], ca0);
    atomicAdd(&scol[c0 + 1], ca1);
    atomicAdd(&scol[c0 + 2], ca2);
    atomicAdd(&scol[c0 + 3], ca3);

    for (int off = 32; off > 0; off >>= 1) {
        s_diff += __shfl_down(s_diff, off);
        s_r2   += __shfl_down(s_r2, off);
        s_w2   += __shfl_down(s_w2, off);
        s_neg  += __shfl_down(s_neg, off);
    }
    if ((tid & 63) == 0) {
        atomicAdd(&ssum[0], s_diff);
        atomicAdd(&ssum[1], s_r2);
        atomicAdd(&ssum[2], s_w2);
        atomicAdd(&ssum[3], s_neg);
    }
    __syncthreads();

    // contiguous per-block partial store
    float* dst = ws + (size_t)blockIdx.x * NPART;
    if (tid < NUM_CITIES)     dst[tid] = scol[tid];
    else if (tid < NPART)     dst[tid] = ssum[tid - NUM_CITIES];
}

// Stage A+B merged: 23 blocks, block q reduces columns 4q..4q+3 over all NBLK
// partial rows via aligned vf4 loads (4x fewer lines than the 92-block scalar
// version); last block (replay-safe (old % 23)==22 counter, no init needed)
// finalizes. Partials come from a PREVIOUS dispatch -> no intra-dispatch
// cross-XCD visibility hazard (round-3 lesson).
__global__ __launch_bounds__(256) void loss_reduce_fin(
    float* __restrict__ ws, float* __restrict__ out)
{
    const int q = blockIdx.x;            // vf4 column group (0..22)
    const int t = threadIdx.x;

    // rows b = t, t+256, ... (11 iterations); 16B-aligned: 368*b + 16*q
    float a0 = 0.f, a1 = 0.f, a2 = 0.f, a3 = 0.f;
    for (int b = t; b < NBLK; b += 256) {
        vf4 x = *(const vf4*)(ws + (size_t)b * NPART + 4 * q);
        a0 += x.x; a1 += x.y; a2 += x.z; a3 += x.w;
    }
    for (int off = 32; off > 0; off >>= 1) {
        a0 += __shfl_down(a0, off);
        a1 += __shfl_down(a1, off);
        a2 += __shfl_down(a2, off);
        a3 += __shfl_down(a3, off);
    }

    __shared__ float s[4][4];
    __shared__ int last;
    if ((t & 63) == 0) {
        const int wv = t >> 6;
        s[wv][0] = a0; s[wv][1] = a1; s[wv][2] = a2; s[wv][3] = a3;
    }
    __syncthreads();
    if (t == 0) {
        float* ws2 = ws + WS2_OFF;
        for (int e = 0; e < 4; ++e)
            ws2[4 * q + e] = s[0][e] + s[1][e] + s[2][e] + s[3][e];
        __threadfence();  // make ws2 visible before signaling
        unsigned old = atomicAdd((unsigned int*)(ws + CTR_OFF), 1u);
        last = ((old % NPART4) == (NPART4 - 1)) ? 1 : 0;
    }
    __syncthreads();
    if (!last) return;

    __threadfence();  // acquire: see all other blocks' ws2 writes
    const float* ws2 = ws + WS2_OFF;
    float v = 0.f;
    if (t < NUM_CITIES)      v = 1e-4f * logf(ws2[t]);
    else if (t == 88)        v = ws2[88];           // diff
    else if (t == 89)        v = 100.f * ws2[89];   // r2 * sg^2/se^2
    else if (t == 90)        v = 0.01f * ws2[90];   // w2 * se^2/sw^2
    else if (t == 91)        v = 100.f * ws2[91];   // neg penalty

    for (int off = 32; off > 0; off >>= 1) v += __shfl_down(v, off);
    __shared__ float sh[4];
    if ((t & 63) == 0) sh[t >> 6] = v;
    __syncthreads();
    if (t == 0) out[0] = sh[0] + sh[1] + sh[2] + sh[3];
}

extern "C" void kernel_launch(void* const* d_in, const int* in_sizes, int n_in,
                              void* d_out, int out_size, void* d_ws, size_t ws_size,
                              hipStream_t stream) {
    const float* G    = (const float*)d_in[0];
    const float* outm = (const float*)d_in[1];
    const float* U    = (const float*)d_in[2];
    // d_in[3] = V, unused by the reference
    const float* D    = (const float*)d_in[4];
    const float* w    = (const float*)d_in[5];
    float* out = (float*)d_out;
    float* ws  = (float*)d_ws;

    loss_main<<<NBLK, 256, 0, stream>>>(G, outm, U, D, w, ws);
    loss_reduce_fin<<<NPART4, 256, 0, stream>>>(ws, out);
}

// Round 6
// 202.858 us; speedup vs baseline: 1.1167x; 1.0105x over previous
//
#include <hip/hip_runtime.h>
#include <math.h>

#define NUM_CITIES 88
#define NUM_YEARS 6
#define N_ROWS 200000

#define COL4 (NUM_CITIES / 4)            // 22 float4 groups per row
#define TOT4 (N_ROWS * COL4)             // 4,400,000 float4 elems in G/D/w
#define DIFF4 (N_ROWS * NUM_YEARS / 4)   // 300,000 float4 elems in U/out

// NBLK = 1760 = 11*160: keeps NTHREADS % 22 == 0 (fixed-column trick: 450560
// = 22*20480) AND 1760 <= 2048 residency capacity (60 VGPR -> 8 blocks/CU) ->
// ALL blocks resident from t=0, zero block churn, only 1.8% CU-quantization
// tail (224 CUs x7 blocks, 32 x6). Round-4's NBLK=2816 was balanced but
// churned 11 block-generations per CU at ~30% occupancy.
#define NBLK 1760
#define NTHREADS (NBLK * 256)            // 450560

#define NPART 92                         // 88 colsums + 4 scalars per block
#define NPART4 (NPART / 4)               // 23 vf4 groups

// 9 guaranteed iterations per thread; tail (10th) for gtid < TAIL_CUT.
#define TAIL_CUT (TOT4 - 9 * NTHREADS)   // 344960

// ws layout: [NBLK][NPART] contiguous partials, then 92 stage-2 sums, then
// 1 atomic counter word for the last-block handoff inside the 2nd dispatch.
#define WS2_OFF (NBLK * NPART)
#define CTR_OFF (WS2_OFF + NPART)

typedef float vf4 __attribute__((ext_vector_type(4)));

// NONTEMPORAL loads are essential (round-1/2 A/B: plain cached loads = 2x
// slower at identical FETCH_SIZE; the 221 MB stream has zero reuse and L2
// allocation throttles the fill path). nt bypasses allocation.
static __device__ __forceinline__ vf4 ldnt4(const float* p) {
    return __builtin_nontemporal_load((const vf4*)p);
}

__global__ __launch_bounds__(256) void loss_main(
    const float* __restrict__ G,
    const float* __restrict__ outm,
    const float* __restrict__ U,
    const float* __restrict__ D,
    const float* __restrict__ w,
    float* __restrict__ ws)
{
    __shared__ float scol[NUM_CITIES];
    __shared__ float ssum[4];

    const int tid = threadIdx.x;
    const int gtid = blockIdx.x * blockDim.x + tid;
    const int c0 = (gtid % COL4) * 4;    // fixed column group (NTHREADS % 22 == 0)

    float ca0 = 0.f, ca1 = 0.f, ca2 = 0.f, ca3 = 0.f;
    float s_r2 = 0.f, s_w2 = 0.f, s_neg = 0.f;

#define ACC(g, d, v)                                                          \
    {                                                                         \
        ca0 += fabsf(g.x); ca1 += fabsf(g.y);                                 \
        ca2 += fabsf(g.z); ca3 += fabsf(g.w);                                 \
        float r0 = g.x - v.x * d.x, r1 = g.y - v.y * d.y;                     \
        float r2 = g.z - v.z * d.z, r3 = g.w - v.w * d.w;                     \
        s_r2 += r0 * r0 + r1 * r1 + r2 * r2 + r3 * r3;                        \
        s_w2 += v.x * v.x + v.y * v.y + v.z * v.z + v.w * v.w;                \
        s_neg += fminf(g.x, 0.f) + fminf(g.y, 0.f)                            \
               + fminf(g.z, 0.f) + fminf(g.w, 0.f);                          \
    }

    // 3 bursts x 3 iterations: 9 vf4 loads in flight per burst keeps register
    // live-ranges short (8 waves/SIMD) while TLP (all blocks resident) hides
    // the inter-burst latency.
#define BURST(k0)                                                             \
    {                                                                         \
        vf4 ga = ldnt4(G + 4 * ((size_t)gtid + (k0 + 0) * (size_t)NTHREADS)); \
        vf4 gb = ldnt4(G + 4 * ((size_t)gtid + (k0 + 1) * (size_t)NTHREADS)); \
        vf4 gc = ldnt4(G + 4 * ((size_t)gtid + (k0 + 2) * (size_t)NTHREADS)); \
        vf4 da = ldnt4(D + 4 * ((size_t)gtid + (k0 + 0) * (size_t)NTHREADS)); \
        vf4 db = ldnt4(D + 4 * ((size_t)gtid + (k0 + 1) * (size_t)NTHREADS)); \
        vf4 dc = ldnt4(D + 4 * ((size_t)gtid + (k0 + 2) * (size_t)NTHREADS)); \
        vf4 va = ldnt4(w + 4 * ((size_t)gtid + (k0 + 0) * (size_t)NTHREADS)); \
        vf4 vb = ldnt4(w + 4 * ((size_t)gtid + (k0 + 1) * (size_t)NTHREADS)); \
        vf4 vc = ldnt4(w + 4 * ((size_t)gtid + (k0 + 2) * (size_t)NTHREADS)); \
        ACC(ga, da, va) ACC(gb, db, vb) ACC(gc, dc, vc)                       \
    }

    BURST(0) BURST(3) BURST(6)
#undef BURST

    // tail iteration (stride preserves gtid % 22 -> same column group)
    if (gtid < TAIL_CUT) {
        vf4 g = ldnt4(G + 4 * ((size_t)gtid + 9 * (size_t)NTHREADS));
        vf4 d = ldnt4(D + 4 * ((size_t)gtid + 9 * (size_t)NTHREADS));
        vf4 v = ldnt4(w + 4 * ((size_t)gtid + 9 * (size_t)NTHREADS));
        ACC(g, d, v)
    }
#undef ACC

    // ---- (U - out)^2 over first 5 of every 6 columns, float4-vectorized ----
    // float4 j covers year-columns (4j..4j+3) mod 6:
    //   j%3==0 -> keep all; j%3==1 -> drop elem 1; j%3==2 -> drop elem 3
    float s_diff = 0.f;
    if (gtid < DIFF4) {
        vf4 u = ldnt4(U + 4 * (size_t)gtid), o = ldnt4(outm + 4 * (size_t)gtid);
        const int m = gtid % 3;
        float e0 = u.x - o.x, e1 = u.y - o.y, e2 = u.z - o.z, e3 = u.w - o.w;
        s_diff = e0 * e0 + e2 * e2
               + ((m != 1) ? e1 * e1 : 0.f)
               + ((m != 2) ? e3 * e3 : 0.f);
    }

    // ---- block-level reduction (LDS only) ----
    if (tid < NUM_CITIES) scol[tid] = 0.f;
    if (tid < 4) ssum[tid] = 0.f;
    __syncthreads();

    atomicAdd(&scol[c0 + 0], ca0);
    atomicAdd(&scol[c0 + 1], ca1);
    atomicAdd(&scol[c0 + 2], ca2);
    atomicAdd(&scol[c0 + 3], ca3);

    for (int off = 32; off > 0; off >>= 1) {
        s_diff += __shfl_down(s_diff, off);
        s_r2   += __shfl_down(s_r2, off);
        s_w2   += __shfl_down(s_w2, off);
        s_neg  += __shfl_down(s_neg, off);
    }
    if ((tid & 63) == 0) {
        atomicAdd(&ssum[0], s_diff);
        atomicAdd(&ssum[1], s_r2);
        atomicAdd(&ssum[2], s_w2);
        atomicAdd(&ssum[3], s_neg);
    }
    __syncthreads();

    // contiguous per-block partial store
    float* dst = ws + (size_t)blockIdx.x * NPART;
    if (tid < NUM_CITIES)     dst[tid] = scol[tid];
    else if (tid < NPART)     dst[tid] = ssum[tid - NUM_CITIES];
}

// Stage A+B merged: 23 blocks, block q reduces columns 4q..4q+3 over all NBLK
// partial rows via aligned vf4 loads; last block (replay-safe (old % 23)==22
// counter, no init needed) finalizes. Partials come from a PREVIOUS dispatch
// -> no intra-dispatch cross-XCD visibility hazard (round-3 lesson).
__global__ __launch_bounds__(256) void loss_reduce_fin(
    float* __restrict__ ws, float* __restrict__ out)
{
    const int q = blockIdx.x;            // vf4 column group (0..22)
    const int t = threadIdx.x;

    // rows b = t, t+256, ... ; 16B-aligned: 368*b + 16*q
    float a0 = 0.f, a1 = 0.f, a2 = 0.f, a3 = 0.f;
    for (int b = t; b < NBLK; b += 256) {
        vf4 x = *(const vf4*)(ws + (size_t)b * NPART + 4 * q);
        a0 += x.x; a1 += x.y; a2 += x.z; a3 += x.w;
    }
    for (int off = 32; off > 0; off >>= 1) {
        a0 += __shfl_down(a0, off);
        a1 += __shfl_down(a1, off);
        a2 += __shfl_down(a2, off);
        a3 += __shfl_down(a3, off);
    }

    __shared__ float s[4][4];
    __shared__ int last;
    if ((t & 63) == 0) {
        const int wv = t >> 6;
        s[wv][0] = a0; s[wv][1] = a1; s[wv][2] = a2; s[wv][3] = a3;
    }
    __syncthreads();
    if (t == 0) {
        float* ws2 = ws + WS2_OFF;
        for (int e = 0; e < 4; ++e)
            ws2[4 * q + e] = s[0][e] + s[1][e] + s[2][e] + s[3][e];
        __threadfence();  // make ws2 visible before signaling
        unsigned old = atomicAdd((unsigned int*)(ws + CTR_OFF), 1u);
        last = ((old % NPART4) == (NPART4 - 1)) ? 1 : 0;
    }
    __syncthreads();
    if (!last) return;

    __threadfence();  // acquire: see all other blocks' ws2 writes
    const float* ws2 = ws + WS2_OFF;
    float v = 0.f;
    if (t < NUM_CITIES)      v = 1e-4f * logf(ws2[t]);
    else if (t == 88)        v = ws2[88];           // diff
    else if (t == 89)        v = 100.f * ws2[89];   // r2 * sg^2/se^2
    else if (t == 90)        v = 0.01f * ws2[90];   // w2 * se^2/sw^2
    else if (t == 91)        v = 100.f * ws2[91];   // neg penalty

    for (int off = 32; off > 0; off >>= 1) v += __shfl_down(v, off);
    __shared__ float sh[4];
    if ((t & 63) == 0) sh[t >> 6] = v;
    __syncthreads();
    if (t == 0) out[0] = sh[0] + sh[1] + sh[2] + sh[3];
}

extern "C" void kernel_launch(void* const* d_in, const int* in_sizes, int n_in,
                              void* d_out, int out_size, void* d_ws, size_t ws_size,
                              hipStream_t stream) {
    const float* G    = (const float*)d_in[0];
    const float* outm = (const float*)d_in[1];
    const float* U    = (const float*)d_in[2];
    // d_in[3] = V, unused by the reference
    const float* D    = (const float*)d_in[4];
    const float* w    = (const float*)d_in[5];
    float* out = (float*)d_out;
    float* ws  = (float*)d_ws;

    loss_main<<<NBLK, 256, 0, stream>>>(G, outm, U, D, w, ws);
    loss_reduce_fin<<<NPART4, 256, 0, stream>>>(ws, out);
}